// Round 17
// baseline (6059.229 us; speedup 1.0000x reference)
//
#include <hip/hip_runtime.h>
#include <stdint.h>

// B=256,T=512,H=256,4 layers. Round 27 = Round 26 + occupancy pinned from BOTH sides.
//  - R25/R26 both spilled (VGPR_Count=128): backend targets LDS-implied occupancy
//    (69.76KB -> 2 WG/CU -> 4 waves/SIMD -> 128 VGPR budget); launch_bounds /
//    waves_per_eu(1,2) only PERMIT more regs, they don't retarget the allocator.
//  - Fix (a): amdgpu_waves_per_eu(2,2) — exact pin, budget 512/2 = 256 VGPR.
//  - Fix (b): dynamic-LDS request padded to 96KB -> LDS-implied occupancy itself
//    becomes 1 WG/CU = 2 waves/SIMD, so the heuristic agrees even if (a) is
//    ignored. Kernel body byte-identical to R26 (512-thr, 2 slices/WG, 4 WG/cell,
//    grain-4 counters, R22-proven primitives).
//  - Decision rule: VGPR still 128 => this shape is untestable; revert to R24.
#define T_ 512
#define H_ 256
#define MB 32
#define NBUF 8
#define ISLOT 8192     // shorts per h image: 16 frag rows x 512 (16 KB)
#define NWG 128
#define NT 512

typedef __attribute__((ext_vector_type(8))) short  short8;
typedef __attribute__((ext_vector_type(4))) float  floatx4;
typedef __attribute__((ext_vector_type(4))) unsigned int uint4v;

struct Params {
  const float* x;
  const float* Wih[4]; const float* Whh[4]; const float* bih[4]; const float* bhh[4];
  const float* fcW; const float* fcb;
  int*   flags;   // [32 cells][32 ints]; int[0] = step counter (grain 4)
  int*   xcd;     // [128] XCC_ID+1 per WG (handshake)
  short* hring;   // [32 cells][NBUF][ISLOT] h images (exact A-fragment layout)
};

__device__ __forceinline__ short f2bf(float f){
  uint32_t u = __builtin_bit_cast(uint32_t, f);
  u += 0x7fffu + ((u >> 16) & 1u);          // RNE
  return (short)(u >> 16);
}
__device__ __forceinline__ float bf2f(short s){
  uint32_t u = ((uint32_t)(uint16_t)s) << 16;
  return __builtin_bit_cast(float, u);
}
__device__ __forceinline__ float sigm(float v){ return 1.0f / (1.0f + __expf(-v)); }
__device__ __forceinline__ float tanh_(float v){
  float a = fabsf(v);
  float e = __expf(-2.0f * a);
  float r = (1.0f - e) / (1.0f + e);
  return v < 0.0f ? -r : r;
}

// ---- agent-scope helpers (handshake + slow-path counters; IF-level, L1-immune) --
__device__ __forceinline__ void a_st32(unsigned* p, unsigned v){
  __hip_atomic_store(p, v, __ATOMIC_RELAXED, __HIP_MEMORY_SCOPE_AGENT);
}
__device__ __forceinline__ int a_ldi(const int* p){
  return __hip_atomic_load(p, __ATOMIC_RELAXED, __HIP_MEMORY_SCOPE_AGENT);
}
__device__ __forceinline__ void a_sti(int* p, int v){
  __hip_atomic_store(p, v, __ATOMIC_RELAXED, __HIP_MEMORY_SCOPE_AGENT);
}

// ---- fast-path flag primitives: L2 atomics (never served by L1) ----
// Sample and waitcnt in ONE asm block — never split (R12/R17 lesson).
__device__ __forceinline__ int ctr_poll_l2(const int* p){
  int v; int z = 0;
  asm volatile("global_atomic_add %0, %1, %2, off sc0\n\t"
               "s_waitcnt vmcnt(0)"
               : "=v"(v) : "v"(p), "v"(z) : "memory");
  return v;
}
__device__ __forceinline__ void ctr_post_l2(int* p){
  int one = 1;
  asm volatile("global_atomic_add %0, %1, off" :: "v"(p), "v"(one) : "memory");
}
template<bool SL> __device__ __forceinline__ int ctr_sample(const int* p){
  if constexpr (SL) return __hip_atomic_fetch_add((int*)p, 0, __ATOMIC_RELAXED,
                                                  __HIP_MEMORY_SCOPE_AGENT);
  else              return ctr_poll_l2(p);
}
template<bool SL> __device__ __forceinline__ void ctr_bump(int* p){
  if constexpr (SL) (void)__hip_atomic_fetch_add(p, 1, __ATOMIC_RELAXED,
                                                 __HIP_MEMORY_SCOPE_AGENT);
  else              ctr_post_l2(p);
}

// ---- data path, scope-templated: SL=true -> IF (sc0 sc1), SL=false -> L2 (sc0)
template<bool SL> __device__ __forceinline__ void ld16t(uint4v& d, const void* p){
  if constexpr (SL) asm volatile("global_load_dwordx4 %0, %1, off sc0 sc1" : "=v"(d) : "v"(p));
  else              asm volatile("global_load_dwordx4 %0, %1, off sc0"     : "=v"(d) : "v"(p));
}
template<bool SL> __device__ __forceinline__ void st32t(unsigned* p, unsigned v){
  if constexpr (SL) a_st32(p, v);
  else asm volatile("global_store_dword %0, %1, off sc0" :: "v"(p), "v"(v) : "memory");
}
// Direct global->LDS 16B load (fast path h staging; dst = wave-uniform + lane*16).
typedef __attribute__((address_space(1))) const void as1void;
typedef __attribute__((address_space(3))) void       as3void;
__device__ __forceinline__ void gld_lds16(const void* g, void* l){
  __builtin_amdgcn_global_load_lds((as1void*)g, (as3void*)l, 16, 0, 1);
}
// L1 invalidate (R13-proven for the data path).
__device__ __forceinline__ void inv_l1(){
  asm volatile("buffer_inv sc0" ::: "memory");
}

__device__ __forceinline__ void ldf32(float& d, const void* p){
  asm volatile("global_load_dword %0, %1, off" : "=v"(d) : "v"(p));
}
__device__ __forceinline__ void waitvm0(){
  asm volatile("s_waitcnt vmcnt(0)" ::: "memory");
}
__device__ __forceinline__ void bar_lds(){   // LDS-visibility barrier
  asm volatile("s_waitcnt lgkmcnt(0)" ::: "memory");
  __builtin_amdgcn_s_barrier();
}
__device__ __forceinline__ void bar_only(){
  __builtin_amdgcn_s_barrier();
}

#define MFMA(a,b,c) __builtin_amdgcn_mfma_f32_16x16x32_bf16((a),(b),(c),0,0,0)

// poll (wave 0 only; lanes 0..2 sample up to 3 cell counters). Grain 4
// (4 WGs/cell post 1 each per step): self>=4t, up>=4(t+2), down>=4(t-4) at
// t%4==0 only. t=-1 => prologue (up>=4). s_sleep(1) backoff. <=1-step spread
// within a cell (self-gate induction) makes counter thr == min-over-WGs thr.
template<bool SL>
__device__ __forceinline__ void cpoll(const int* self, const int* up, const int* down,
                                      int t, bool& dead){
  if (dead) return;
  const int lane = threadIdx.x & 63;
  const int* p = nullptr; int thr = 0;
  if (lane == 0)            { p = self; thr = t; }
  else if (lane == 1 && up) { p = up;   thr = t + 2; }
  else if (lane == 2 && down && ((t & 3) == 0)){ p = down; thr = t - 4; }
  if (thr > T_) thr = T_;
  thr <<= 2;                                   // grain 4
  int guard = 0;
  for (;;){
    int v = p ? ctr_sample<SL>(p) : 0x7fffffff;
    if (__all((int)(v >= thr))) break;
    __builtin_amdgcn_s_sleep(1);
    if (++guard > (1 << 14)) { dead = true; break; }
  }
}

template<bool L0, bool SL>
__device__ __forceinline__ void run_cell(const Params& p, int g, int l, int q,
    short* a_frag, float (*g_lds)[4][MB][34], float (*bias_lds)[4][32],
    float (*wih0_lds)[4][32], float* x0_lds)
{
  constexpr int KBT = L0 ? 8 : 16;
  const int tid = threadIdx.x, lane = tid & 63, wave = tid >> 6;   // 8 waves
  const int sub = wave >> 2, gate = wave & 3;                      // 2 sub-slices
  const int slice = q * 2 + sub;                                   // global slice 0..7
  const int n15 = lane & 15, q4 = lane >> 4;
  const int cell = g * 4 + l;

  int* ctr_self = p.flags + cell * 32;
  const int* ctr_up   = L0 ? (const int*)nullptr : ctr_self - 32;
  const int* ctr_down = (l < 3) ? ctr_self + 32 : (const int*)nullptr;
  short* hr_self = p.hring + (size_t)(cell * NBUF) * ISLOT;
  const short* hr_up = L0 ? (const short*)nullptr
                          : hr_self - (size_t)NBUF * ISLOT;

  if (tid < 256){
    int sb = tid >> 7, gt = (tid >> 5) & 3, j = tid & 31;
    int gr = gt * 256 + (q * 2 + sb) * 32 + j;
    bias_lds[sb][gt][j] = p.bih[l][gr] + p.bhh[l][gr];
    if (L0) wih0_lds[sb][gt][j] = p.Wih[0][gr];    // W_ih0 is [1024 x 1]
  }

  // ---- Weight B-fragments resident in VGPRs (r6/r9-proven mapping) ----
  short8 wf0[KBT], wf1[KBT];
  const int g0 = gate * 256 + slice * 32 + n15;
  const int g1 = g0 + 16;
  #pragma unroll
  for (int kb = 0; kb < KBT; ++kb){
    const float* base; int kk;
    if (L0)          { base = p.Whh[0]; kk = kb * 32 + q4 * 8; }
    else if (kb < 8) { base = p.Wih[l]; kk = kb * 32 + q4 * 8; }
    else             { base = p.Whh[l]; kk = (kb - 8) * 32 + q4 * 8; }
    const float* p0 = base + (size_t)g0 * H_ + kk;
    const float* p1 = base + (size_t)g1 * H_ + kk;
    short8 a, b;
    #pragma unroll
    for (int i = 0; i < 8; ++i){ a[i] = f2bf(p0[i]); b[i] = f2bf(p1[i]); }
    wf0[kb] = a; wf1[kb] = b;
  }

  float c00 = 0.f, c01 = 0.f, c10 = 0.f, c11 = 0.f;
  const int sub_p = tid >> 8, st = tid & 255;       // pointwise decomposition
  const int r0 = (st >> 4) * 2, r1 = r0 + 1;
  const int pc = (st & 15) * 2;
  const int slice_p = q * 2 + sub_p;
  bool dead = false;

  uint4v* fragv = (uint4v*)a_frag;
  uint4v px[2];
  float xcur = 0.f;
  const int hbase = L0 ? 0 : 1024;            // u128 index of h region

  auto gates_out = [&](floatx4 (&acc)[2][2][2]){
    #pragma unroll
    for (int mt = 0; mt < 2; ++mt){
      floatx4 s0 = acc[mt][0][0] + acc[mt][0][1];
      floatx4 s1 = acc[mt][1][0] + acc[mt][1][1];
      int mrow = mt * 16 + q4 * 4;
      #pragma unroll
      for (int r = 0; r < 4; ++r){
        g_lds[sub][gate][mrow + r][n15]      = s0[r];
        g_lds[sub][gate][mrow + r][16 + n15] = s1[r];
      }
    }
  };
  auto pointwise = [&](int t){
    float xs0 = 0.f, xs1 = 0.f;
    if (L0){ xs0 = x0_lds[r0]; xs1 = x0_lds[r1]; }
    float2 bi = *(const float2*)&bias_lds[sub_p][0][pc];
    float2 bf = *(const float2*)&bias_lds[sub_p][1][pc];
    float2 bg = *(const float2*)&bias_lds[sub_p][2][pc];
    float2 bo = *(const float2*)&bias_lds[sub_p][3][pc];
    float2 wi = {0.f,0.f}, wf = {0.f,0.f}, wg = {0.f,0.f}, wo = {0.f,0.f};
    if (L0){
      wi = *(const float2*)&wih0_lds[sub_p][0][pc];
      wf = *(const float2*)&wih0_lds[sub_p][1][pc];
      wg = *(const float2*)&wih0_lds[sub_p][2][pc];
      wo = *(const float2*)&wih0_lds[sub_p][3][pc];
    }
    short* slot = hr_self + (size_t)(t & 7) * ISLOT;
    #pragma unroll
    for (int rr = 0; rr < 2; ++rr){
      const int row = rr ? r1 : r0;
      const float xs = rr ? xs1 : xs0;
      float2 vi = *(const float2*)&g_lds[sub_p][0][row][pc];
      float2 vf = *(const float2*)&g_lds[sub_p][1][row][pc];
      float2 vg = *(const float2*)&g_lds[sub_p][2][row][pc];
      float2 vo = *(const float2*)&g_lds[sub_p][3][row][pc];
      float gi0 = vi.x + bi.x, gi1 = vi.y + bi.y;
      float gf0 = vf.x + bf.x, gf1 = vf.y + bf.y;
      float gg0 = vg.x + bg.x, gg1 = vg.y + bg.y;
      float go0 = vo.x + bo.x, go1 = vo.y + bo.y;
      if (L0){
        gi0 += xs * wi.x; gi1 += xs * wi.y;
        gf0 += xs * wf.x; gf1 += xs * wf.y;
        gg0 += xs * wg.x; gg1 += xs * wg.y;
        go0 += xs * wo.x; go1 += xs * wo.y;
      }
      float i0 = sigm(gi0), i1 = sigm(gi1);
      float f0 = sigm(gf0), f1 = sigm(gf1);
      float gv0 = tanh_(gg0), gv1 = tanh_(gg1);
      float o0 = sigm(go0), o1 = sigm(go1);
      float& ca = rr ? c10 : c00;
      float& cb = rr ? c11 : c01;
      ca = f0 * ca + i0 * gv0;
      cb = f1 * cb + i1 * gv1;
      float h0 = o0 * tanh_(ca);
      float h1 = o1 * tanh_(cb);
      unsigned pk = (unsigned)(uint16_t)f2bf(h0) | ((unsigned)(uint16_t)f2bf(h1) << 16);
      unsigned off = (unsigned)((slice_p * 2 + (row >> 4)) * 512
                   + ((pc >> 3) * 16 + (row & 15)) * 8 + (pc & 7));
      st32t<SL>((unsigned*)(slot + off), pk);
    }
  };

  if constexpr (!L0){
    // ---- Prologue: load x(0) image (slot 0 of up ring) ----
    if (wave == 0) cpoll<SL>(ctr_self, ctr_up, ctr_down, -1, dead);   // up >= 4
    __syncthreads();
    if constexpr (!SL) inv_l1();
    { const char* s = (const char*)hr_up;
      #pragma unroll
      for (int k = 0; k < 2; ++k) ld16t<SL>(px[k], s + (size_t)(k * 512 + tid) * 16); }
    waitvm0();
    __syncthreads();

    for (int t = 0; t < T_; ++t){
      const bool havh = (t > 0);
      const bool pf = (t + 1 < T_);
      floatx4 acc[2][2][2] = {};
      uint4v hv[2];                                  // slow path only
      // stage x(t) (lane-contiguous, conflict-free)
      #pragma unroll
      for (int k = 0; k < 2; ++k) fragv[k * 512 + tid] = px[k];
      bar_lds();   // bar1: x visible
      // kb0-3 x-MFMA (hides the poll detect)
      #pragma unroll
      for (int kb = 0; kb < 4; ++kb){
        #pragma unroll
        for (int mt = 0; mt < 2; ++mt){
          short8 af = *(short8*)&a_frag[(kb * 2 + mt) * 512 + lane * 8];
          int pr = kb & 1;
          acc[mt][0][pr] = MFMA(af, wf0[kb], acc[mt][0][pr]);
          acc[mt][1][pr] = MFMA(af, wf1[kb], acc[mt][1][pr]);
        }
      }
      if (wave == 0) cpoll<SL>(ctr_self, ctr_up, ctr_down, t, dead);  // blocking, fused
      bar_only();  // bar1b: verdict gates h/px issue
      if constexpr (!SL){
        inv_l1();
        if (havh){
          const char* s = (const char*)(hr_self + (size_t)((t - 1) & 7) * ISLOT);
          #pragma unroll
          for (int k = 0; k < 2; ++k){
            const char* src = s + (size_t)(k * 512 + tid) * 16;
            gld_lds16(src, (void*)&fragv[hbase + k * 512 + (tid & ~63)]);
          }
        }
      } else {
        if (havh){
          const char* s = (const char*)(hr_self + (size_t)((t - 1) & 7) * ISLOT);
          #pragma unroll
          for (int k = 0; k < 2; ++k) ld16t<SL>(hv[k], s + (size_t)(k * 512 + tid) * 16);
        }
      }
      if (pf){
        const char* s = (const char*)(hr_up + (size_t)((t + 1) & 7) * ISLOT);
        #pragma unroll
        for (int k = 0; k < 2; ++k) ld16t<SL>(px[k], s + (size_t)(k * 512 + tid) * 16);
      }
      // kb4-7 x-MFMA (hides h/px RT)
      #pragma unroll
      for (int kb = 4; kb < 8; ++kb){
        #pragma unroll
        for (int mt = 0; mt < 2; ++mt){
          short8 af = *(short8*)&a_frag[(kb * 2 + mt) * 512 + lane * 8];
          int pr = kb & 1;
          acc[mt][0][pr] = MFMA(af, wf0[kb], acc[mt][0][pr]);
          acc[mt][1][pr] = MFMA(af, wf1[kb], acc[mt][1][pr]);
        }
      }
      waitvm0();                                 // h in LDS (fast) / regs (slow)
      if constexpr (SL){
        if (havh){
          #pragma unroll
          for (int k = 0; k < 2; ++k) fragv[hbase + k * 512 + tid] = hv[k];
        }
      }
      if (!havh){
        uint4v z = {0, 0, 0, 0};
        #pragma unroll
        for (int k = 0; k < 2; ++k) fragv[hbase + k * 512 + tid] = z;
      }
      bar_lds();   // bar2: h rows visible
      // h-MFMA kb8-15
      #pragma unroll
      for (int kb = 8; kb < 16; ++kb){
        #pragma unroll
        for (int mt = 0; mt < 2; ++mt){
          short8 af = *(short8*)&a_frag[(kb * 2 + mt) * 512 + lane * 8];
          int pr = kb & 1;
          acc[mt][0][pr] = MFMA(af, wf0[kb], acc[mt][0][pr]);
          acc[mt][1][pr] = MFMA(af, wf1[kb], acc[mt][1][pr]);
        }
      }
      gates_out(acc);
      bar_lds();   // bar3: gates visible
      pointwise(t);
      waitvm0();   // own stores drained (L2 ACK fast / IF slow)
      bar_only();  // bar4: all waves drained
      if (tid == 0) ctr_bump<SL>(ctr_self);        // single post per WG
    }
  } else {
    // ================= L0: same shape, x is a scalar stream =================
    if (wave == 0 && lane < MB) ldf32(xcur, &p.x[(size_t)(g * MB + lane) * T_]);
    waitvm0();
    __syncthreads();

    for (int t = 0; t < T_; ++t){
      const bool havh = (t > 0);
      const bool pf = (t + 1 < T_);
      floatx4 acc[2][2][2] = {};
      uint4v hv[2];
      if (wave == 0) cpoll<SL>(ctr_self, (const int*)nullptr, ctr_down, t, dead);
      if (wave == 0 && lane < MB) x0_lds[lane] = xcur;
      bar_lds();   // bar1: x0 staged; verdict propagated
      if constexpr (!SL){
        inv_l1();
        if (havh){
          const char* s = (const char*)(hr_self + (size_t)((t - 1) & 7) * ISLOT);
          #pragma unroll
          for (int k = 0; k < 2; ++k){
            const char* src = s + (size_t)(k * 512 + tid) * 16;
            gld_lds16(src, (void*)&fragv[hbase + k * 512 + (tid & ~63)]);
          }
        }
      } else {
        if (havh){
          const char* s = (const char*)(hr_self + (size_t)((t - 1) & 7) * ISLOT);
          #pragma unroll
          for (int k = 0; k < 2; ++k) ld16t<SL>(hv[k], s + (size_t)(k * 512 + tid) * 16);
        }
      }
      if (wave == 0 && lane < MB && pf){
        ldf32(xcur, &p.x[(size_t)(g * MB + lane) * T_ + (t + 1)]);
      }
      waitvm0();
      if constexpr (SL){
        if (havh){
          #pragma unroll
          for (int k = 0; k < 2; ++k) fragv[hbase + k * 512 + tid] = hv[k];
        }
      }
      if (!havh){
        uint4v z = {0, 0, 0, 0};
        #pragma unroll
        for (int k = 0; k < 2; ++k) fragv[hbase + k * 512 + tid] = z;
      }
      bar_lds();   // bar2: h rows visible
      // h-MFMA kb0-7
      #pragma unroll
      for (int kb = 0; kb < 8; ++kb){
        #pragma unroll
        for (int mt = 0; mt < 2; ++mt){
          short8 af = *(short8*)&a_frag[(kb * 2 + mt) * 512 + lane * 8];
          int pr = kb & 1;
          acc[mt][0][pr] = MFMA(af, wf0[kb], acc[mt][0][pr]);
          acc[mt][1][pr] = MFMA(af, wf1[kb], acc[mt][1][pr]);
        }
      }
      gates_out(acc);
      bar_lds();   // bar3
      pointwise(t);
      waitvm0();
      bar_only();  // bar4
      if (tid == 0) ctr_bump<SL>(ctr_self);
    }
  }
}

__global__ __attribute__((amdgpu_flat_work_group_size(NT, NT), amdgpu_waves_per_eu(2, 2)))
void lstm_kernel(Params p){
  extern __shared__ char smem[];
  short* a_frag                  = (short*)smem;                     // 32768 B
  float (*g_lds)[4][MB][34]      = (float (*)[4][MB][34])(smem + 32768);   // 34816 B
  float (*bias_lds)[4][32]       = (float (*)[4][32])(smem + 67584); // 1024 B
  float (*wih0_lds)[4][32]       = (float (*)[4][32])(smem + 68608); // 1024 B
  float* x0_lds                  = (float*)(smem + 69632);           // 128 B
  __shared__ int fsh;

  // bid = q*32 + l*8 + g : all 16 WGs of group g share bid%8 -> same XCD.
  const int bid = blockIdx.x;
  const int g   = bid & 7;
  const int l   = (bid >> 3) & 3;
  const int q   = bid >> 5;                   // quarter 0..3 (2 slices each)

  // ---- XCD co-location handshake (128 WGs co-resident on 256 CUs) ----
  int xcc;
  asm volatile("s_getreg_b32 %0, hwreg(HW_REG_XCC_ID)" : "=s"(xcc));
  const int me = xcc + 1;
  if (threadIdx.x == 0) a_sti(&p.xcd[bid], me);
  int fast;
  {
    const int lane = threadIdx.x & 63;
    const int idx = lane & 15;                // 16 group members: (q',l') = (idx>>2, idx&3)
    const int* xp = p.xcd + (idx >> 2) * 32 + (idx & 3) * 8 + g;
    int v = 0, guard = 0; bool giveup = false;
    for (;;){
      v = a_ldi(xp);
      if (__all((int)(v != 0))) break;
      if (++guard > (1 << 22)) { giveup = true; break; }
    }
    fast = (!giveup && __all((int)(v == me))) ? 1 : 0;
  }
  if (threadIdx.x == 0) fsh = 1;
  __syncthreads();
  if (!fast) fsh = 0;                          // benign race, all writers store 0
  __syncthreads();
  fast = fsh;

  if (l == 0){
    if (fast) run_cell<true , false>(p, g, 0, q, a_frag, g_lds, bias_lds, wih0_lds, x0_lds);
    else      run_cell<true , true >(p, g, 0, q, a_frag, g_lds, bias_lds, wih0_lds, x0_lds);
  } else {
    if (fast) run_cell<false, false>(p, g, l, q, a_frag, g_lds, bias_lds, wih0_lds, x0_lds);
    else      run_cell<false, true >(p, g, l, q, a_frag, g_lds, bias_lds, wih0_lds, x0_lds);
  }
}

// FC on h_3(T-1): decode fragment image, cell (g,3), ring slot (T-1)&7 = 7.
// (Dispatch-boundary L2 writeback makes fast-path sc0 stores visible here.)
__global__ void fc_kernel(const short* __restrict__ hring, const float* __restrict__ fcW,
                          const float* __restrict__ fcb, float* __restrict__ out){
  int b = blockIdx.x, lane = threadIdx.x;
  int g = b >> 5, m = b & 31;
  int mt = m >> 4, mm = m & 15;
  const short* base = hring + (size_t)((g * 4 + 3) * NBUF + ((T_ - 1) & 7)) * ISLOT;
  float s = 0.f;
  #pragma unroll
  for (int k = 0; k < 4; ++k){
    int d = lane + 64 * k;
    int kb = d >> 5, koff = d & 31;
    short hv = base[(kb * 2 + mt) * 512 + ((koff >> 3) * 16 + mm) * 8 + (koff & 7)];
    s += bf2f(hv) * fcW[d];
  }
  #pragma unroll
  for (int off = 32; off; off >>= 1) s += __shfl_down(s, off);
  if (lane == 0) out[b] = s + fcb[0];
}

extern "C" void kernel_launch(void* const* d_in, const int* in_sizes, int n_in,
                              void* d_out, int out_size, void* d_ws, size_t ws_size,
                              hipStream_t stream) {
  Params P;
  P.x = (const float*)d_in[0];
  for (int l = 0; l < 4; ++l){
    P.Wih[l] = (const float*)d_in[1 + 4*l];
    P.Whh[l] = (const float*)d_in[2 + 4*l];
    P.bih[l] = (const float*)d_in[3 + 4*l];
    P.bhh[l] = (const float*)d_in[4 + 4*l];
  }
  P.fcW = (const float*)d_in[17];
  P.fcb = (const float*)d_in[18];

  char* ws = (char*)d_ws;
  P.flags = (int*)ws;                        // 32 lines x 128 B = 4 KB
  P.xcd   = (int*)(ws + 4096);               // 128 ints (zeroed by memset)
  P.hring = (short*)(ws + 16384);            // 32 x 8 x 16 KB = 4 MB

  hipMemsetAsync(ws, 0, 8192, stream);
  // 96 KB dynamic-LDS request: forces LDS-implied occupancy to 1 WG/CU so the
  // register allocator targets 2 waves/SIMD (256 VGPR budget). Extra LDS unused.
  hipLaunchKernelGGL(lstm_kernel, dim3(NWG), dim3(NT), 98304, stream, P);
  hipLaunchKernelGGL(fc_kernel, dim3(256), dim3(64), 0, stream,
                     P.hring, P.fcW, P.fcb, (float*)d_out);
}

// Round 18
// 1530.594 us; speedup vs baseline: 3.9587x; 3.9587x over previous
//
#include <hip/hip_runtime.h>
#include <stdint.h>

// B=256,T=512,H=256,4 layers. Round 28 = R22 verbatim (session best, 1541us).
//  - R25-R27: 512-thr decomposition untestable (hard 128-VGPR budget at 512 thr;
//    launch_bounds / waves_per_eu / LDS-padding all ignored -> spill). LESSON:
//    weight-in-VGPR designs need <=256 threads/WG on this toolchain.
//  - R22 structure: 256-thr, 8 slices/cell, poll hidden under x-MFMA kb0-3
//    (the one overlap that measured real: -7%), gld_lds16 h staging, counted
//    vmcnt(4) px prefetch, L2 atomic counters (fused RMW+waitcnt, never split),
//    sc0 data + inv_l1, 1 post/WG, agent-scope slow fallback.
//  - Remaining gap to ideal is the latency floor of this decomposition
//    (8-party zero-slack rendezvous + L2 RT chain at 1 wave/SIMD); all
//    mechanism perturbations (R18/R20/R21/R24) measured null.
#define T_ 512
#define H_ 256
#define MB 32
#define NBUF 8
#define ISLOT 8192     // shorts per h image: 16 frag rows x 512 (16 KB)
#define NWG 256

typedef __attribute__((ext_vector_type(8))) short  short8;
typedef __attribute__((ext_vector_type(4))) float  floatx4;
typedef __attribute__((ext_vector_type(4))) unsigned int uint4v;
typedef unsigned long long ull;

struct Params {
  const float* x;
  const float* Wih[4]; const float* Whh[4]; const float* bih[4]; const float* bhh[4];
  const float* fcW; const float* fcb;
  int*   flags;   // [8g][4l][32 ints], one 128B line per (g,l); fast path: int[0]=counter
  int*   xcd;     // [256] XCC_ID+1 per WG (handshake)
  short* hring;   // [8g][4l][NBUF][ISLOT] h images (exact A-fragment layout)
};

__device__ __forceinline__ short f2bf(float f){
  uint32_t u = __builtin_bit_cast(uint32_t, f);
  u += 0x7fffu + ((u >> 16) & 1u);          // RNE
  return (short)(u >> 16);
}
__device__ __forceinline__ float bf2f(short s){
  uint32_t u = ((uint32_t)(uint16_t)s) << 16;
  return __builtin_bit_cast(float, u);
}
__device__ __forceinline__ float sigm(float v){ return 1.0f / (1.0f + __expf(-v)); }
__device__ __forceinline__ float tanh_(float v){
  float a = fabsf(v);
  float e = __expf(-2.0f * a);
  float r = (1.0f - e) / (1.0f + e);
  return v < 0.0f ? -r : r;
}

// ---- agent-scope atomics (slow-path flag protocol + handshake; R10-proven) ----
__device__ __forceinline__ void a_st32(unsigned* p, unsigned v){
  __hip_atomic_store(p, v, __ATOMIC_RELAXED, __HIP_MEMORY_SCOPE_AGENT);
}
__device__ __forceinline__ int a_ldi(const int* p){
  return __hip_atomic_load(p, __ATOMIC_RELAXED, __HIP_MEMORY_SCOPE_AGENT);
}
__device__ __forceinline__ void a_sti(int* p, int v){
  __hip_atomic_store(p, v, __ATOMIC_RELAXED, __HIP_MEMORY_SCOPE_AGENT);
}

// ---- fast-path flag primitives: L2 atomics (never served by L1) ----
// Sample and waitcnt in ONE asm block — never split (R12/R17 lesson).
__device__ __forceinline__ int ctr_poll(const int* p){
  int v; int z = 0;
  asm volatile("global_atomic_add %0, %1, %2, off sc0\n\t"
               "s_waitcnt vmcnt(0)"
               : "=v"(v) : "v"(p), "v"(z) : "memory");
  return v;
}
__device__ __forceinline__ void ctr_post(int* p){
  int one = 1;
  asm volatile("global_atomic_add %0, %1, off" :: "v"(p), "v"(one) : "memory");
}

// ---- data path, scope-templated: SL=true -> IF (sc0 sc1), SL=false -> L2 (sc0)
template<bool SL> __device__ __forceinline__ void ld16t(uint4v& d, const void* p){
  if constexpr (SL) asm volatile("global_load_dwordx4 %0, %1, off sc0 sc1" : "=v"(d) : "v"(p));
  else              asm volatile("global_load_dwordx4 %0, %1, off sc0"     : "=v"(d) : "v"(p));
}
template<bool SL> __device__ __forceinline__ void st32t(unsigned* p, unsigned v){
  if constexpr (SL) a_st32(p, v);
  else asm volatile("global_store_dword %0, %1, off sc0" :: "v"(p), "v"(v) : "memory");
}
// Direct global->LDS 16B load (fast path h staging; dst = wave-uniform + lane*16).
typedef __attribute__((address_space(1))) const void as1void;
typedef __attribute__((address_space(3))) void       as3void;
__device__ __forceinline__ void gld_lds16(const void* g, void* l){
  __builtin_amdgcn_global_load_lds((as1void*)g, (as3void*)l, 16, 0, 1);
}
// L1 invalidate (R13-proven for the data path).
__device__ __forceinline__ void inv_l1(){
  asm volatile("buffer_inv sc0" ::: "memory");
}

__device__ __forceinline__ void ldf32(float& d, const void* p){
  asm volatile("global_load_dword %0, %1, off" : "=v"(d) : "v"(p));
}
template<int N> __device__ __forceinline__ void waitvm(){
  if constexpr (N == 0) asm volatile("s_waitcnt vmcnt(0)" ::: "memory");
  else if constexpr (N == 1) asm volatile("s_waitcnt vmcnt(1)" ::: "memory");
  else                       asm volatile("s_waitcnt vmcnt(4)" ::: "memory");
}
__device__ __forceinline__ void bar_lds(){   // LDS-visibility barrier, VM ops keep flying
  asm volatile("s_waitcnt lgkmcnt(0)" ::: "memory");
  __builtin_amdgcn_s_barrier();
}
__device__ __forceinline__ void bar_only(){
  __builtin_amdgcn_s_barrier();
}

#define MFMA(a,b,c) __builtin_amdgcn_mfma_f32_16x16x32_bf16((a),(b),(c),0,0,0)

// slow-path poll (agent scope, all waves) — R10/R13-proven
__device__ __forceinline__ void wpoll(const int* p, int thr, bool& dead){
  if (dead) return;
  int guard = 0;
  for (;;){
    int v = a_ldi(p);
    if (__all((int)(v >= thr))) break;
    if (++guard > (1 << 16)) { dead = true; break; }
  }
}

// fast-path poll (wave 0 only; lanes 0..2 sample up to 3 cell counters at L2).
// thresholds (grain 8): self>=8t, up>=8(t+2), down>=8(t-4) at t%4==0 only.
// t=-1 => prologue (up>=8, others trivial). s_sleep(1) backoff on failed sample.
__device__ __forceinline__ void cpoll(const int* self, const int* up, const int* down,
                                      int t, bool& dead){
  if (dead) return;
  const int lane = threadIdx.x & 63;
  const int* p = nullptr; int thr = 0;
  if (lane == 0)            { p = self; thr = t; }
  else if (lane == 1 && up) { p = up;   thr = t + 2; }
  else if (lane == 2 && down && ((t & 3) == 0)){ p = down; thr = t - 4; }
  if (thr > T_) thr = T_;
  thr <<= 3;
  int guard = 0;
  for (;;){
    int v = p ? ctr_poll(p) : 0x7fffffff;
    if (__all((int)(v >= thr))) break;
    __builtin_amdgcn_s_sleep(1);
    if (++guard > (1 << 14)) { dead = true; break; }
  }
}

template<bool L0, bool SL>
__device__ __forceinline__ void run_cell(const Params& p, int g, int l, int slice,
    short* a_frag, float (*g_lds)[MB][34], float (*bias_lds)[32],
    float (*wih0_lds)[32], float* x0_lds)
{
  constexpr int KBT = L0 ? 8 : 16;
  const int tid = threadIdx.x, lane = tid & 63, wave = tid >> 6;  // wave = gate
  const int n15 = lane & 15, q4 = lane >> 4;

  int* fl_self = p.flags + (g * 4 + l) * 32;
  int* fl_up   = L0 ? fl_self : fl_self - 32;
  int* fl_down = (l < 3) ? fl_self + 32 : fl_self;
  short* hr_self = p.hring + (size_t)((g * 4 + l) * NBUF) * ISLOT;
  const short* hr_up = L0 ? (const short*)nullptr
                          : hr_self - (size_t)NBUF * ISLOT;

  // fast-path counters (int[0] of each cell's flag line)
  int* ctr_self = fl_self;
  const int* ctr_up   = L0 ? (const int*)nullptr : fl_self - 32;
  const int* ctr_down = (l < 3) ? fl_self + 32 : (const int*)nullptr;

  if (tid < 128){
    int gt = tid >> 5, j = tid & 31;
    int gr = gt * 256 + slice * 32 + j;
    bias_lds[gt][j] = p.bih[l][gr] + p.bhh[l][gr];
    if (L0) wih0_lds[gt][j] = p.Wih[0][gr];    // W_ih0 is [1024 x 1]
  }

  // ---- Weight B-fragments resident in VGPRs (r6/r9-proven mapping) ----
  short8 wf0[KBT], wf1[KBT];
  const int g0 = wave * 256 + slice * 32 + n15;
  const int g1 = g0 + 16;
  #pragma unroll
  for (int kb = 0; kb < KBT; ++kb){
    const float* base; int kk;
    if (L0)          { base = p.Whh[0]; kk = kb * 32 + q4 * 8; }
    else if (kb < 8) { base = p.Wih[l]; kk = kb * 32 + q4 * 8; }
    else             { base = p.Whh[l]; kk = (kb - 8) * 32 + q4 * 8; }
    const float* p0 = base + (size_t)g0 * H_ + kk;
    const float* p1 = base + (size_t)g1 * H_ + kk;
    short8 a, b;
    #pragma unroll
    for (int i = 0; i < 8; ++i){ a[i] = f2bf(p0[i]); b[i] = f2bf(p1[i]); }
    wf0[kb] = a; wf1[kb] = b;
  }

  float c00 = 0.f, c01 = 0.f, c10 = 0.f, c11 = 0.f;
  const int r0 = (tid >> 4) * 2, r1 = r0 + 1;
  const int pc = (tid & 15) * 2;

  // slow-path merged poll map (all waves; R10-proven)
  const int* pp; int dlt;
  if (lane < 8)      { pp = fl_self + lane; dlt = 0; }
  else if (lane < 16){ if (L0){ pp = fl_self; dlt = -1000000; }
                       else   { pp = fl_up + (lane - 8); dlt = 2; } }
  else if (lane < 24){ if (l < 3){ pp = fl_down + (lane - 16); dlt = -7; }
                       else      { pp = fl_self; dlt = -1000000; } }
  else               { pp = fl_self + (lane & 7); dlt = -1000000; }
  bool dead = false;

  uint4v* fragv = (uint4v*)a_frag;
  uint4v px[4];
  float xcur = 0.f;

  // ---- Prologue: x(0) ----
  if (!L0){
    if constexpr (SL){
      wpoll(fl_up + (lane & 7), 1, dead);
    } else {
      if (wave == 0) cpoll(ctr_self, ctr_up, ctr_down, -1, dead);  // up >= 8
      __syncthreads();
      inv_l1();
    }
    const char* s = (const char*)hr_up;            // slot 0
    #pragma unroll
    for (int k = 0; k < 4; ++k) ld16t<SL>(px[k], s + (size_t)(k * 256 + tid) * 16);
  } else if (wave == 0 && lane < MB){
    ldf32(xcur, &p.x[(size_t)(g * MB + lane) * T_]);
  }
  waitvm<0>();
  __syncthreads();

  for (int t = 0; t < T_; ++t){
    const bool havh = (t > 0);
    const bool pf = (t + 1 < T_);
    const int hbase = L0 ? 0 : 1024;            // u128 index of h region
    uint4v hv[4];                               // slow path only
    floatx4 acc[2][2][2] = {};

    if constexpr (SL){
      // ---- slow path: R10/R21 shape, byte-identical behavior ----
      { int thr = t + dlt; if (thr > T_) thr = T_;
        wpoll(pp, thr, dead); }
      if (!L0){
        #pragma unroll
        for (int k = 0; k < 4; ++k) fragv[k * 256 + tid] = px[k];
      } else if (wave == 0 && lane < MB){
        x0_lds[lane] = xcur;
      }
      if (havh){
        const char* s = (const char*)(hr_self + (size_t)((t - 1) & 7) * ISLOT);
        #pragma unroll
        for (int k = 0; k < 4; ++k) ld16t<SL>(hv[k], s + (size_t)(k * 256 + tid) * 16);
      }
      if (!L0){
        if (pf){
          const char* s = (const char*)(hr_up + (size_t)((t + 1) & 7) * ISLOT);
          #pragma unroll
          for (int k = 0; k < 4; ++k) ld16t<SL>(px[k], s + (size_t)(k * 256 + tid) * 16);
        }
      } else if (wave == 0 && lane < MB && pf){
        ldf32(xcur, &p.x[(size_t)(g * MB + lane) * T_ + (t + 1)]);
      }
      bar_lds();   // bar1
      if (!L0){
        #pragma unroll
        for (int kb = 0; kb < 8; ++kb){
          #pragma unroll
          for (int mt = 0; mt < 2; ++mt){
            short8 af = *(short8*)&a_frag[(kb * 2 + mt) * 512 + lane * 8];
            int pr = kb & 1;
            acc[mt][0][pr] = MFMA(af, wf0[kb], acc[mt][0][pr]);
            acc[mt][1][pr] = MFMA(af, wf1[kb], acc[mt][1][pr]);
          }
        }
      }
      if (!L0){ if (pf) waitvm<4>(); else waitvm<0>(); }
      else    { if (wave == 0 && pf) waitvm<1>(); else waitvm<0>(); }
      if (havh){
        #pragma unroll
        for (int k = 0; k < 4; ++k) fragv[hbase + k * 256 + tid] = hv[k];
      } else {
        uint4v z = {0, 0, 0, 0};
        #pragma unroll
        for (int k = 0; k < 4; ++k) fragv[hbase + k * 256 + tid] = z;
      }
      bar_lds();   // bar2
    } else if constexpr (!L0){
      // ---- fast path, !L0: detect hidden under x-MFMA (safe fused poll) ----
      #pragma unroll
      for (int k = 0; k < 4; ++k) fragv[k * 256 + tid] = px[k];   // stage x
      bar_lds();   // bar1: x rows visible
      #pragma unroll
      for (int kb = 0; kb < 4; ++kb){                             // x-MFMA kb0..3
        #pragma unroll
        for (int mt = 0; mt < 2; ++mt){
          short8 af = *(short8*)&a_frag[(kb * 2 + mt) * 512 + lane * 8];
          int pr = kb & 1;
          acc[mt][0][pr] = MFMA(af, wf0[kb], acc[mt][0][pr]);
          acc[mt][1][pr] = MFMA(af, wf1[kb], acc[mt][1][pr]);
        }
      }
      if (wave == 0) cpoll(ctr_self, ctr_up, ctr_down, t, dead);  // blocking, fused
      bar_only();  // bar1b: verdict gates h/px issue
      inv_l1();
      if (havh){
        const char* s = (const char*)(hr_self + (size_t)((t - 1) & 7) * ISLOT);
        #pragma unroll
        for (int k = 0; k < 4; ++k){
          const char* src = s + (size_t)(k * 256 + tid) * 16;
          gld_lds16(src, (void*)&fragv[hbase + k * 256 + (tid & ~63)]);
        }
      }
      if (pf){
        const char* s = (const char*)(hr_up + (size_t)((t + 1) & 7) * ISLOT);
        #pragma unroll
        for (int k = 0; k < 4; ++k) ld16t<SL>(px[k], s + (size_t)(k * 256 + tid) * 16);
      }
      #pragma unroll
      for (int kb = 4; kb < 8; ++kb){                             // x-MFMA kb4..7 hides h RT
        #pragma unroll
        for (int mt = 0; mt < 2; ++mt){
          short8 af = *(short8*)&a_frag[(kb * 2 + mt) * 512 + lane * 8];
          int pr = kb & 1;
          acc[mt][0][pr] = MFMA(af, wf0[kb], acc[mt][0][pr]);
          acc[mt][1][pr] = MFMA(af, wf1[kb], acc[mt][1][pr]);
        }
      }
      if (pf) waitvm<4>(); else waitvm<0>();
      if (!havh){
        uint4v z = {0, 0, 0, 0};
        #pragma unroll
        for (int k = 0; k < 4; ++k) fragv[hbase + k * 256 + tid] = z;
      }
      bar_lds();   // bar2: h rows visible (lds-direct tracked by vmcnt above)
    } else {
      // ---- fast path, L0: R21 shape (blocking poll at top) ----
      if (wave == 0) cpoll(ctr_self, ctr_up, ctr_down, t, dead);
      if (wave == 0 && lane < MB) x0_lds[lane] = xcur;
      bar_lds();   // bar1
      inv_l1();
      if (havh){
        const char* s = (const char*)(hr_self + (size_t)((t - 1) & 7) * ISLOT);
        #pragma unroll
        for (int k = 0; k < 4; ++k){
          const char* src = s + (size_t)(k * 256 + tid) * 16;
          gld_lds16(src, (void*)&fragv[hbase + k * 256 + (tid & ~63)]);
        }
      }
      if (wave == 0 && lane < MB && pf){
        ldf32(xcur, &p.x[(size_t)(g * MB + lane) * T_ + (t + 1)]);
      }
      if (wave == 0 && pf) waitvm<1>(); else waitvm<0>();
      if (!havh){
        uint4v z = {0, 0, 0, 0};
        #pragma unroll
        for (int k = 0; k < 4; ++k) fragv[hbase + k * 256 + tid] = z;
      }
      bar_lds();   // bar2
    }

    // h-part MFMA
    #pragma unroll
    for (int kb = (L0 ? 0 : 8); kb < KBT; ++kb){
      #pragma unroll
      for (int mt = 0; mt < 2; ++mt){
        short8 af = *(short8*)&a_frag[(kb * 2 + mt) * 512 + lane * 8];
        int pr = kb & 1;
        acc[mt][0][pr] = MFMA(af, wf0[kb], acc[mt][0][pr]);
        acc[mt][1][pr] = MFMA(af, wf1[kb], acc[mt][1][pr]);
      }
    }
    #pragma unroll
    for (int mt = 0; mt < 2; ++mt){
      floatx4 s0 = acc[mt][0][0] + acc[mt][0][1];
      floatx4 s1 = acc[mt][1][0] + acc[mt][1][1];
      int mrow = mt * 16 + q4 * 4;
      #pragma unroll
      for (int r = 0; r < 4; ++r){
        g_lds[wave][mrow + r][n15]      = s0[r];
        g_lds[wave][mrow + r][16 + n15] = s1[r];
      }
    }
    bar_lds();   // bar3: gates visible

    // pointwise -> packed u32 into fragment-image ring (r9-proven mapping)
    {
      float xs0 = 0.f, xs1 = 0.f;
      if (L0){ xs0 = x0_lds[r0]; xs1 = x0_lds[r1]; }
      float2 bi = *(const float2*)&bias_lds[0][pc];
      float2 bf = *(const float2*)&bias_lds[1][pc];
      float2 bg = *(const float2*)&bias_lds[2][pc];
      float2 bo = *(const float2*)&bias_lds[3][pc];
      float2 wi = {0.f,0.f}, wf = {0.f,0.f}, wg = {0.f,0.f}, wo = {0.f,0.f};
      if (L0){
        wi = *(const float2*)&wih0_lds[0][pc];
        wf = *(const float2*)&wih0_lds[1][pc];
        wg = *(const float2*)&wih0_lds[2][pc];
        wo = *(const float2*)&wih0_lds[3][pc];
      }
      short* slot = hr_self + (size_t)(t & 7) * ISLOT;
      #pragma unroll
      for (int rr = 0; rr < 2; ++rr){
        const int row = rr ? r1 : r0;
        const float xs = rr ? xs1 : xs0;
        float2 vi = *(const float2*)&g_lds[0][row][pc];
        float2 vf = *(const float2*)&g_lds[1][row][pc];
        float2 vg = *(const float2*)&g_lds[2][row][pc];
        float2 vo = *(const float2*)&g_lds[3][row][pc];
        float gi0 = vi.x + bi.x, gi1 = vi.y + bi.y;
        float gf0 = vf.x + bf.x, gf1 = vf.y + bf.y;
        float gg0 = vg.x + bg.x, gg1 = vg.y + bg.y;
        float go0 = vo.x + bo.x, go1 = vo.y + bo.y;
        if (L0){
          gi0 += xs * wi.x; gi1 += xs * wi.y;
          gf0 += xs * wf.x; gf1 += xs * wf.y;
          gg0 += xs * wg.x; gg1 += xs * wg.y;
          go0 += xs * wo.x; go1 += xs * wo.y;
        }
        float i0 = sigm(gi0), i1 = sigm(gi1);
        float f0 = sigm(gf0), f1 = sigm(gf1);
        float gv0 = tanh_(gg0), gv1 = tanh_(gg1);
        float o0 = sigm(go0), o1 = sigm(go1);
        float& ca = rr ? c10 : c00;
        float& cb = rr ? c11 : c01;
        ca = f0 * ca + i0 * gv0;
        cb = f1 * cb + i1 * gv1;
        float h0 = o0 * tanh_(ca);
        float h1 = o1 * tanh_(cb);
        unsigned pk = (unsigned)(uint16_t)f2bf(h0) | ((unsigned)(uint16_t)f2bf(h1) << 16);
        unsigned off = (unsigned)((slice * 2 + (row >> 4)) * 512
                     + ((pc >> 3) * 16 + (row & 15)) * 8 + (pc & 7));
        st32t<SL>((unsigned*)(slot + off), pk);
      }
    }

    // bar4: h stores drained (L2 ACK on fast path); then post (same scope)
    waitvm<0>();
    bar_only();
    if (tid == 0){
      if constexpr (SL) a_sti(fl_self + slice, t + 1);
      else              ctr_post(ctr_self);
    }
  }
}

__global__ __launch_bounds__(256, 1) void lstm_kernel(Params p){
  __shared__ short a_frag[32 * 512];          // 32 KB (x rows 0..15, h rows 16..31)
  __shared__ float g_lds[4][MB][34];
  __shared__ float bias_lds[4][32];
  __shared__ float wih0_lds[4][32];
  __shared__ float x0_lds[MB];
  __shared__ int   fsh;

  // Remap so all 32 WGs of a group share bid%8 -> same XCD under round-robin.
  const int bid   = blockIdx.x;
  const int g     = bid & 7;
  const int l     = (bid >> 3) & 3;
  const int slice = bid >> 5;

  // ---- XCD co-location handshake (all 256 WGs are co-resident on 256 CUs) ----
  int xcc;
  asm volatile("s_getreg_b32 %0, hwreg(HW_REG_XCC_ID)" : "=s"(xcc));
  const int me = xcc + 1;
  if (threadIdx.x == 0) a_sti(&p.xcd[bid], me);
  int fast;
  {
    const int lane = threadIdx.x & 63;
    const int idx = lane & 31;                 // 32 group members: bid' = s*32 + ll*8 + g
    const int* xp = p.xcd + (idx >> 2) * 32 + (idx & 3) * 8 + g;
    int v = 0, guard = 0; bool giveup = false;
    for (;;){
      v = a_ldi(xp);
      if (__all((int)(v != 0))) break;
      if (++guard > (1 << 22)) { giveup = true; break; }  // unreachable in practice
    }
    fast = (!giveup && __all((int)(v == me))) ? 1 : 0;
  }
  if (threadIdx.x == 0) fsh = 1;
  __syncthreads();
  if (!fast) fsh = 0;                          // benign race, all writers store 0
  __syncthreads();
  fast = fsh;

  if (l == 0){
    if (fast) run_cell<true , false>(p, g, 0, slice, a_frag, g_lds, bias_lds, wih0_lds, x0_lds);
    else      run_cell<true , true >(p, g, 0, slice, a_frag, g_lds, bias_lds, wih0_lds, x0_lds);
  } else {
    if (fast) run_cell<false, false>(p, g, l, slice, a_frag, g_lds, bias_lds, wih0_lds, x0_lds);
    else      run_cell<false, true >(p, g, l, slice, a_frag, g_lds, bias_lds, wih0_lds, x0_lds);
  }
}

// FC on h_3(T-1): decode fragment image, cell (g,3), ring slot (T-1)&7 = 7.
// (Dispatch-boundary L2 writeback makes fast-path sc0 stores visible here.)
__global__ void fc_kernel(const short* __restrict__ hring, const float* __restrict__ fcW,
                          const float* __restrict__ fcb, float* __restrict__ out){
  int b = blockIdx.x, lane = threadIdx.x;
  int g = b >> 5, m = b & 31;
  int mt = m >> 4, mm = m & 15;
  const short* base = hring + (size_t)((g * 4 + 3) * NBUF + ((T_ - 1) & 7)) * ISLOT;
  float s = 0.f;
  #pragma unroll
  for (int k = 0; k < 4; ++k){
    int d = lane + 64 * k;
    int kb = d >> 5, koff = d & 31;
    short hv = base[(kb * 2 + mt) * 512 + ((koff >> 3) * 16 + mm) * 8 + (koff & 7)];
    s += bf2f(hv) * fcW[d];
  }
  #pragma unroll
  for (int off = 32; off; off >>= 1) s += __shfl_down(s, off);
  if (lane == 0) out[b] = s + fcb[0];
}

extern "C" void kernel_launch(void* const* d_in, const int* in_sizes, int n_in,
                              void* d_out, int out_size, void* d_ws, size_t ws_size,
                              hipStream_t stream) {
  Params P;
  P.x = (const float*)d_in[0];
  for (int l = 0; l < 4; ++l){
    P.Wih[l] = (const float*)d_in[1 + 4*l];
    P.Whh[l] = (const float*)d_in[2 + 4*l];
    P.bih[l] = (const float*)d_in[3 + 4*l];
    P.bhh[l] = (const float*)d_in[4 + 4*l];
  }
  P.fcW = (const float*)d_in[17];
  P.fcb = (const float*)d_in[18];

  char* ws = (char*)d_ws;
  P.flags = (int*)ws;                        // 32 lines x 128 B = 4 KB
  P.xcd   = (int*)(ws + 4096);               // 256 ints = 1 KB (zeroed by memset)
  P.hring = (short*)(ws + 16384);            // 32 x 8 x 16 KB = 4 MB

  hipMemsetAsync(ws, 0, 8192, stream);
  hipLaunchKernelGGL(lstm_kernel, dim3(NWG), dim3(256), 0, stream, P);
  hipLaunchKernelGGL(fc_kernel, dim3(256), dim3(64), 0, stream,
                     P.hring, P.fcW, P.fcb, (float*)d_out);
}